// Round 1
// baseline (238.185 us; speedup 1.0000x reference)
//
#include <hip/hip_runtime.h>
#include <hip/hip_bf16.h>

#define NB 16
#define NC 4
#define NN 100
#define NL 192
#define NF 97
#define ND 128
#define NM 16
#define NH 8
#define NHD 16
#define NP 96
#define NR (NB*NC*NN)   /* 6400 */
#define NBC (NB*NC)     /* 64 */
#define KP1 224         /* padded K for weight-space: [xr(97)|xi(97)|pad(30)] */

typedef __bf16 bf16x8 __attribute__((ext_vector_type(8)));
typedef float f32x4 __attribute__((ext_vector_type(4)));
typedef float f32x16 __attribute__((ext_vector_type(16)));
typedef short s16x8 __attribute__((ext_vector_type(8)));
typedef short s16x4 __attribute__((ext_vector_type(4)));
typedef float f32x4v __attribute__((ext_vector_type(4)));

__device__ __forceinline__ float bf2f(unsigned short u){
  union { unsigned int i; float f; } x; x.i = ((unsigned int)u) << 16; return x.f;
}
__device__ __forceinline__ unsigned short f2bf(float v){
  __hip_bfloat16 h = __float2bfloat16(v);
  return *reinterpret_cast<unsigned short*>(&h);
}

// ---------------- merged elementwise precompute: tt | wbig | wg1 | wop | cast ----------------
__global__ void k_prep(const float* __restrict__ fw,
                       const float* __restrict__ fc1_wr, const float* __restrict__ fc1_wi,
                       const float* __restrict__ tr_, const float* __restrict__ ti_,
                       const float* __restrict__ fc4_wr, const float* __restrict__ fc4_wi,
                       const float* __restrict__ op1_w, const float* __restrict__ op2_w,
                       const float* __restrict__ xp,
                       unsigned short* __restrict__ Tt, unsigned short* __restrict__ Wbig,
                       unsigned short* __restrict__ Wg1,
                       unsigned short* __restrict__ Wop1, unsigned short* __restrict__ Wop2,
                       unsigned short* __restrict__ Xpb, unsigned short* __restrict__ Xpbf){
  int b = blockIdx.x, c = threadIdx.x;
  if (b < 256){                                  // Tt[256,224]
    if (c >= KP1) return;
    int l = b;
    float v = 0.f;
    if (l < NL && c < 2*NF){
      int f = (c < NF) ? c : c - NF;
      float s = 1.f/(1.f+expf(-fw[f]));
      int ph = (f*l) % NL;
      float ang = (float)ph * (6.283185307179586f/(float)NL);
      float sv, cv; sincosf(ang, &sv, &cv);
      v = (c < NF) ? s*cv : -s*sv;
    }
    Tt[(size_t)l*KP1 + c] = f2bf(v);
  } else if (b < 256+4096){                      // Wbig[4096,224]
    if (c >= KP1) return;
    int nIdx = b - 256;
    int m = nIdx >> 8, p = (nIdx >> 7) & 1, d = nIdx & 127;
    float v = 0.f;
    if (c < 2*NF){
      int f = (c < NF) ? c : c - NF;
      float tr = tr_[m*NF+f], ti = ti_[m*NF+f];
      float wr_ = fc1_wr[d*NF+f], wi_ = fc1_wi[d*NF+f];
      float w1r = tr*wr_ - ti*wi_;
      float w1i = tr*wi_ + ti*wr_;
      if (p == 0) v = (c < NF) ? w1r : -w1i;
      else        v = (c < NF) ? w1i :  w1r;
    }
    Wbig[(size_t)nIdx*KP1 + c] = f2bf(v);
  } else if (b < 256+4096+256){                  // Wg1[256,224]
    if (c >= KP1) return;
    int n = b - (256+4096);
    int p = n >> 7, d = n & 127;
    float v = 0.f;
    if (c < NF) v = p ? fc4_wi[d*NF+c] : fc4_wr[d*NF+c];
    else if (c < 2*NF){
      int f = c - NF;
      v = p ? fc4_wr[d*NF+f] : -fc4_wi[d*NF+f];
    }
    Wg1[(size_t)n*KP1 + c] = f2bf(v);
  } else if (b < 4608+480){                      // wop casts
    int i = (b-4608)*256 + c;
    const int N1 = 384*NL;
    if (i < N1){ Wop1[i] = f2bf(op1_w[i]); return; }
    int j = i - N1;
    if (j < 128*384){
      int n = j / 384, t2 = j - n*384;
      Wop2[j] = f2bf((n < NP) ? op2_w[n*384 + t2] : 0.f);
    }
  } else {                                       // cast xp -> Xpb + Xpbf (600 blocks)
    size_t i = ((size_t)(b-5088)*256 + c)*8;
    f32x4v a = *(const f32x4v*)(xp + i);
    f32x4v bb = *(const f32x4v*)(xp + i + 4);
    s16x8 o;
#pragma unroll
    for (int e=0;e<4;e++){ o[e] = (short)f2bf(a[e]); o[4+e] = (short)f2bf(bb[e]); }
    *(s16x8*)(Xpb + i) = o;
    int row = (int)(i / NL);
    int colg = (int)(i % NL) >> 3;
    int rb = row >> 4, rl = row & 15;
    int ch = colg >> 2, cg = colg & 3;
    int lane = rl + (cg << 4);
    *(s16x8*)(Xpbf + ((((size_t)rb*6 + ch)*64 + lane)*8)) = o;
  }
}

// merged dot-style precompute: comb(+cbias) | wg2(+bg2) | AB
__global__ void k_prep2(const float* __restrict__ fc2_wr, const float* __restrict__ fc2_wi,
                        const float* __restrict__ fc2_br, const float* __restrict__ fc2_bi,
                        const float* __restrict__ ra_wk, const float* __restrict__ ra_bk,
                        const float* __restrict__ ra_wv, const float* __restrict__ ra_bv,
                        const float* __restrict__ ia_wk, const float* __restrict__ ia_bk,
                        const float* __restrict__ ia_wv, const float* __restrict__ ia_bv,
                        const float* __restrict__ fc5_wr, const float* __restrict__ fc5_wi,
                        const float* __restrict__ fc5_br, const float* __restrict__ fc5_bi,
                        const float* __restrict__ ra_wq, const float* __restrict__ ra_bq,
                        const float* __restrict__ ia_wq, const float* __restrict__ ia_bq,
                        const float* __restrict__ fc3_wr, const float* __restrict__ fc3_wi,
                        const float* __restrict__ fc3_br, const float* __restrict__ fc3_bi,
                        unsigned short* __restrict__ comb2f, float* __restrict__ cbias,
                        unsigned short* __restrict__ Wg2, float* __restrict__ bg2,
                        float* __restrict__ A_, float* __restrict__ B_, float* __restrict__ c0_){
  __shared__ float icL[NF], isL[NF];
  int b = blockIdx.x, t = threadIdx.x;
  if (b < 1032){                                  // comb: k = b/8, c = b%8 (k==128 -> cbias)
    if (t >= 128) return;
    int k = b >> 3, c = b & 7, d = t;
    if (k == ND){
      if (c >= 4) return;
      const float* w = ra_wk; const float* bb = ra_bk; const float* fb = fc2_br;
      switch(c){
        case 0: w=ra_wk; bb=ra_bk; fb=fc2_br; break;
        case 1: w=ra_wv; bb=ra_bv; fb=fc2_br; break;
        case 2: w=ia_wk; bb=ia_bk; fb=fc2_bi; break;
        case 3: w=ia_wv; bb=ia_bv; fb=fc2_bi; break;
      }
      float s = bb[d];
      for (int j=0;j<ND;j++) s += w[d*ND+j]*fb[j];
      cbias[c*ND+d] = s;
      return;
    }
    const float* w = ra_wk; const float* f2 = fc2_wr; float sign = 1.f;
    switch(c){
      case 0: w=ra_wk; f2=fc2_wr; sign= 1.f; break;
      case 1: w=ra_wk; f2=fc2_wi; sign=-1.f; break;
      case 2: w=ra_wv; f2=fc2_wr; sign= 1.f; break;
      case 3: w=ra_wv; f2=fc2_wi; sign=-1.f; break;
      case 4: w=ia_wk; f2=fc2_wi; sign= 1.f; break;
      case 5: w=ia_wk; f2=fc2_wr; sign= 1.f; break;
      case 6: w=ia_wv; f2=fc2_wi; sign= 1.f; break;
      case 7: w=ia_wv; f2=fc2_wr; sign= 1.f; break;
    }
    float s = 0.f;
    for (int j=0;j<ND;j++) s += w[d*ND+j]*f2[j*ND+k];
    int cOut = c >> 1, p = c & 1;
    int jj = d >> 4, rl = d & 15;
    int col = p*ND + k;
    int ch = col >> 5, cg = (col >> 3) & 3, e = col & 7;
    int lane = rl + (cg << 4);
    comb2f[((((size_t)(cOut*8 + ch))*8 + jj)*64 + lane)*8 + e] = f2bf(sign*s);
  } else if (b < 1032+512){                       // wg2
    int q = b - 1032, c = t;
    int k = c & 127; bool ti = (c >= 128);
    const float SCL = 0.08838834764831845f;
    float v = 0.f;
    if (q < 128){
      const float* f5 = ti ? fc5_wi : fc5_wr; float sg = ti ? -1.f : 1.f;
      float s = 0.f;
      for (int j=0;j<ND;j++) s += ra_wq[q*ND+j]*f5[j*ND+k];
      v = sg*s*SCL;
    } else if (q < 256){
      int qq = q-128;
      const float* f5 = ti ? fc5_wr : fc5_wi;
      float s = 0.f;
      for (int j=0;j<ND;j++) s += ia_wq[qq*ND+j]*f5[j*ND+k];
      v = s*SCL;
    } else if (q < 384){
      int d = q-256;
      v = ti ? -fc5_wi[d*ND+k] : fc5_wr[d*ND+k];
    } else {
      int d = q-384;
      v = ti ? fc5_wr[d*ND+k] : fc5_wi[d*ND+k];
    }
    Wg2[(size_t)q*256 + c] = f2bf(v);
    if (c == 0){
      float bb;
      if (q < 128){ bb = ra_bq[q]; for (int j=0;j<ND;j++) bb += ra_wq[q*ND+j]*fc5_br[j]; bb *= SCL; }
      else if (q < 256){ int qq=q-128; bb = ia_bq[qq]; for (int j=0;j<ND;j++) bb += ia_wq[qq*ND+j]*fc5_bi[j]; bb *= SCL; }
      else if (q < 384) bb = fc5_br[q-256];
      else bb = fc5_bi[q-384];
      bg2[q] = bb;
    }
  } else {                                        // AB: l = b-1544 (192 blocks)
    int l = b - 1544, d = t;
    if (d < NF){
      float w = ((d==0)||(d==NF-1)) ? 1.f : 2.f;
      w *= (1.f/(float)NL);
      int ph = (d*l) % NL;
      float ang = (float)ph * (6.283185307179586f/(float)NL);
      float sv, cv; sincosf(ang, &sv, &cv);
      icL[d] = w*cv; isL[d] = w*sv;
    }
    __syncthreads();
    if (d < 128){
      float a = 0.f, bb = 0.f;
      for (int f=0;f<NF;f++){
        float ic = icL[f], is = isL[f];
        float wr = fc3_wr[f*ND+d], wi = fc3_wi[f*ND+d];
        a += ic*wr - is*wi;
        bb -= ic*wi + is*wr;
      }
      A_[l*ND+d] = a; B_[l*ND+d] = bb;
      if (d == 0){
        float cc = 0.f;
        for (int f=0;f<NF;f++) cc += icL[f]*fc3_br[f] - isL[f]*fc3_bi[f];
        c0_[l] = cc;
      }
    }
  }
}

__global__ void k_wt1(const float* __restrict__ A_, const float* __restrict__ B_,
                      const float* __restrict__ c0_,
                      const float* __restrict__ ra_wo, const float* __restrict__ ra_bo,
                      const float* __restrict__ ia_wo, const float* __restrict__ ia_bo,
                      unsigned short* __restrict__ WT1, float* __restrict__ bT1){
  int l = blockIdx.x;          // 0..255
  int c = threadIdx.x;         // 0..511
  float v = 0.f;
  if (l < NL){
    if (c < 128) v = A_[l*ND+c];
    else if (c < 256) v = B_[l*ND+(c-128)];
    else if (c < 384){
      int k = c-256; float s = 0.f;
      for (int j=0;j<ND;j++) s += A_[l*ND+j]*ra_wo[j*ND+k];
      v = s;
    } else {
      int k = c-384; float s = 0.f;
      for (int j=0;j<ND;j++) s += B_[l*ND+j]*ia_wo[j*ND+k];
      v = s;
    }
  }
  WT1[(size_t)l*512 + c] = f2bf(v);
  if (c == 0){
    float bb = 0.f;
    if (l < NL){
      bb = c0_[l];
      for (int j=0;j<ND;j++) bb += A_[l*ND+j]*ra_bo[j] + B_[l*ND+j]*ia_bo[j];
    }
    bT1[l] = bb;
  }
}

// ---------------- MFMA GEMM (templated M-tile) ----------------
// MODE 1: dual bias (bit7 of n), relu, bf16 out
// MODE 2: bias b0[n], bf16 out
// MODE 3: bias b0[n], relu, bf16 out
// MODE 4: bias b0[n] (n<96), fp32 out, store guard n<96
// MODE 6: no bias, bf16 out, store guard n<192 (weight-fold, row-major)
// MODE 7: no bias, bf16 out, guard n<192, FRAGMENT-MAJOR store [m][ch][jj][lane][8]
template<int MT, int KT, int MODE>
__global__ __launch_bounds__(256) void k_gemm(
    const unsigned short* __restrict__ A, int lda,
    const unsigned short* __restrict__ Bw,
    const float* __restrict__ b0, const float* __restrict__ b1,
    void* __restrict__ Cv, int ldc)
{
  constexpr int NI = MT/32;                 // M-frags per wave
  __shared__ unsigned short As[MT][40];
  __shared__ unsigned short Bs[128][40];
  int t = threadIdx.x;
  int bm = blockIdx.x, bn = blockIdx.y;
  int w = t >> 6, l = t & 63;
  int wm = w >> 1, wn = w & 1;
  f32x4 acc[NI][4] = {};
  int r0 = t >> 2, c0 = (t & 3) * 8;
  const unsigned short* Ag = A + (size_t)(bm*MT)*lda;
  const unsigned short* Bg = Bw + (size_t)(bn*128)*KT;
  int lr = l & 15, lk = (l >> 4) * 8;
  for (int k0 = 0; k0 < KT; k0 += 32){
    s16x8 a0 = *(const s16x8*)(Ag + (size_t)r0*lda + k0 + c0);
    s16x8 a1;
    if constexpr (MT == 128) a1 = *(const s16x8*)(Ag + (size_t)(r0+64)*lda + k0 + c0);
    s16x8 bv0 = *(const s16x8*)(Bg + (size_t)r0*KT + k0 + c0);
    s16x8 bv1 = *(const s16x8*)(Bg + (size_t)(r0+64)*KT + k0 + c0);
    __syncthreads();
    *(s16x8*)(&As[r0][c0]) = a0;
    if constexpr (MT == 128) *(s16x8*)(&As[r0+64][c0]) = a1;
    *(s16x8*)(&Bs[r0][c0]) = bv0;
    *(s16x8*)(&Bs[r0+64][c0]) = bv1;
    __syncthreads();
    bf16x8 af[NI], bfr[4];
#pragma unroll
    for (int i=0;i<NI;i++) af[i]  = *(const bf16x8*)(&As[wm*(MT/2) + i*16 + lr][lk]);
#pragma unroll
    for (int j=0;j<4;j++) bfr[j] = *(const bf16x8*)(&Bs[wn*64 + j*16 + lr][lk]);
#pragma unroll
    for (int i=0;i<NI;i++)
#pragma unroll
      for (int j=0;j<4;j++)
        acc[i][j] = __builtin_amdgcn_mfma_f32_16x16x32_bf16(af[i], bfr[j], acc[i][j], 0, 0, 0);
  }
  int lr4 = (l >> 4) * 4, lc = l & 15;
#pragma unroll
  for (int i=0;i<NI;i++){
#pragma unroll
    for (int j=0;j<4;j++){
      int n = bn*128 + wn*64 + j*16 + lc;
      float bias;
      if constexpr (MODE == 1) bias = ((n>>7)&1) ? b1[n&127] : b0[n&127];
      else if constexpr (MODE == 4) bias = (n < NP) ? b0[n] : 0.f;
      else if constexpr (MODE == 6 || MODE == 7) bias = 0.f;
      else bias = b0[n];
#pragma unroll
      for (int q=0;q<4;q++){
        int row = bm*MT + wm*(MT/2) + i*16 + lr4 + q;
        float v = acc[i][j][q] + bias;
        if constexpr (MODE == 1 || MODE == 3) v = fmaxf(v, 0.f);
        if constexpr (MODE == 4){
          if (n < NP) ((float*)Cv)[(size_t)row*ldc + n] = v;
        } else if constexpr (MODE == 6){
          if (n < NL) ((unsigned short*)Cv)[(size_t)row*ldc + n] = f2bf(v);
        } else if constexpr (MODE == 7){
          if (n < NL){
            int m2 = row >> 8, rt = row & 255;
            int jj = rt >> 4, rl2 = rt & 15;
            int ch = n >> 5, cg = (n >> 3) & 3, e = n & 7;
            int lane = rl2 + (cg << 4);
            ((unsigned short*)Cv)[((((size_t)(m2*6 + ch))*16 + jj)*64 + lane)*8 + e] = f2bf(v);
          }
        } else {
          ((unsigned short*)Cv)[(size_t)row*ldc + n] = f2bf(v);
        }
      }
    }
  }
}

// ---------------- fused delay path v8: coalesced V stores via LDS bounce ----------------
// grid (100, 16 m); K/V key index kk = m*100 + n
__global__ __launch_bounds__(256, 4) void k_fuse(
    const unsigned short* __restrict__ Xpbf,    // [400][6][64][8] fragment-major
    const unsigned short* __restrict__ Wbig2f,  // [16][6][16][64][8] fragment-major
    const float* __restrict__ fc1_br, const float* __restrict__ fc1_bi,
    const unsigned short* __restrict__ comb2f,  // [4][8][8][64][8] fragment-major
    const float* __restrict__ cbias,            // [512]
    unsigned short* __restrict__ Kg,            // [2][64][8][1600][16]
    unsigned short* __restrict__ Vt)            // [2][64][8][16][1600]
{
  __shared__ unsigned short act2f[8][4][64][8]; // fragment-major act, 32768 B
  __shared__ unsigned short vbuf[128*64];       // 16384 B V bounce [d][kk], XOR-swizzled
  int t = threadIdx.x;
  int bm = blockIdx.x, m = blockIdx.y;
  int w = t >> 6, l = t & 63;
  int wm = w >> 1, wn = w & 1;
  int lc = l & 15, lr4 = (l >> 4) * 4;
  int rbase = bm*64;

  // ---------- phase 1: act[64][256] = relu(X @ Wm^T + b); 0 barriers ----------
  f32x4 acc1[2][8] = {};
  const unsigned short* Af = Xpbf + ((size_t)(bm*4)*6)*512;       // frag stride 64*8=512
  const unsigned short* Bf = Wbig2f + ((size_t)m*6)*16*512;
#pragma unroll 2
  for (int ch = 0; ch < 6; ch++){
    bf16x8 af[2], bfj[8];
#pragma unroll
    for (int i=0;i<2;i++)
      af[i] = *(const bf16x8*)(Af + (((size_t)(wm*2 + i)*6 + ch))*512 + l*8);
#pragma unroll
    for (int j=0;j<8;j++)
      bfj[j] = *(const bf16x8*)(Bf + ((size_t)ch*16 + wn*8 + j)*512 + l*8);
#pragma unroll
    for (int i=0;i<2;i++)
#pragma unroll
      for (int j=0;j<8;j++)
        acc1[i][j] = __builtin_amdgcn_mfma_f32_16x16x32_bf16(af[i], bfj[j], acc1[i][j], 0, 0, 0);
  }
  // epilogue 1: bias + relu -> act2f (fragment-major, 2-way max aliasing)
#pragma unroll
  for (int i=0;i<2;i++){
#pragma unroll
    for (int j=0;j<8;j++){
      int col = wn*128 + j*16 + lc;
      float bias = ((col>>7)&1) ? fc1_bi[col&127] : fc1_br[col&127];
      int ch = col >> 5, cg = (col >> 3) & 3, e = col & 7;
#pragma unroll
      for (int q=0;q<4;q++)
        act2f[ch][wm*2 + i][(lr4 + q) + (cg << 4)][e] = f2bf(fmaxf(acc1[i][j][q] + bias, 0.f));
    }
  }
  __syncthreads();

  // ---------- phase 2: KV[64][512] in 4 n-tiles; K tiles operand-swapped ----------
  for (int bn2 = 0; bn2 < 4; bn2++){
    const unsigned short* Cf = comb2f + ((size_t)bn2*8)*8*512;
    int call = bn2 >> 1, isV = bn2 & 1;
    if (!isV){
      // K: C^T = comb x act -> quad spans d; dense 8B vector stores
      f32x4 accS[4][2] = {};
#pragma unroll 2
      for (int ch = 0; ch < 8; ch++){
        bf16x8 af[2], bfr[4];
#pragma unroll
        for (int i=0;i<2;i++)
          af[i] = *(const bf16x8*)(&act2f[ch][wm*2 + i][l][0]);
#pragma unroll
        for (int j=0;j<4;j++)
          bfr[j] = *(const bf16x8*)(Cf + ((size_t)ch*8 + wn*4 + j)*512 + l*8);
#pragma unroll
        for (int j=0;j<4;j++)
#pragma unroll
          for (int i=0;i<2;i++)
            accS[j][i] = __builtin_amdgcn_mfma_f32_16x16x32_bf16(bfr[j], af[i], accS[j][i], 0, 0, 0);
      }
#pragma unroll
      for (int j=0;j<4;j++){
        int n2q = wn*64 + j*16 + lr4;          // quad base in n2 (d dim)
        f32x4v cb4 = *(const f32x4v*)(cbias + bn2*128 + n2q);
        int h = n2q >> 4, d0 = n2q & 15;
#pragma unroll
        for (int i=0;i<2;i++){
          int rr = rbase + wm*32 + i*16 + lc;
          int bc = rr/100, n = rr - bc*100;
          int kk = m*100 + n;
          s16x4 v4;
#pragma unroll
          for (int q=0;q<4;q++) v4[q] = (short)f2bf(accS[j][i][q] + cb4[q]);
          *(s16x4*)(Kg + ((((size_t)(call*NBC + bc))*8 + h)*1600 + kk)*16 + d0) = v4;
        }
      }
    } else {
      // V: normal orientation; stage to swizzled LDS then coalesced 128B-run stores
      f32x4 acc[2][4] = {};
#pragma unroll 2
      for (int ch = 0; ch < 8; ch++){
        bf16x8 af[2], bfr[4];
#pragma unroll
        for (int i=0;i<2;i++)
          af[i] = *(const bf16x8*)(&act2f[ch][wm*2 + i][l][0]);
#pragma unroll
        for (int j=0;j<4;j++)
          bfr[j] = *(const bf16x8*)(Cf + ((size_t)ch*8 + wn*4 + j)*512 + l*8);
#pragma unroll
        for (int i=0;i<2;i++)
#pragma unroll
          for (int j=0;j<4;j++)
            acc[i][j] = __builtin_amdgcn_mfma_f32_16x16x32_bf16(af[i], bfr[j], acc[i][j], 0, 0, 0);
      }
      // epilogue: bias + cast into vbuf[d=n2][kk_local], byte ^= ((d&7)<<4)
#pragma unroll
      for (int i=0;i<2;i++){
        int kkl = wm*32 + i*16 + lr4;          // quad spans kk_local..+3
#pragma unroll
        for (int j=0;j<4;j++){
          int n2 = wn*64 + j*16 + lc;
          float bias = cbias[bn2*128 + n2];
          s16x4 v4;
#pragma unroll
          for (int q=0;q<4;q++) v4[q] = (short)f2bf(acc[i][j][q] + bias);
          *(s16x4*)((char*)vbuf + ((n2*128 + kkl*2) ^ ((n2&7)<<4))) = v4;
        }
      }
      // lgkm-only barrier: keep outstanding global stores in flight
      asm volatile("s_waitcnt lgkmcnt(0)" ::: "memory");
      __builtin_amdgcn_s_barrier();
      // cooperative store: thread t -> 16B chunk c of d-row; 8 lanes = 128B run
      {
        int c = t & 7, dbase = t >> 3;
        int r0 = rbase + c*8;
        int bc0 = r0/100, n0 = r0 - bc0*100;     // n0 multiple of 4; straddle iff n0==96
#pragma unroll
        for (int p=0;p<4;p++){
          int d = dbase + p*32;
          union { s16x8 v; s16x4 h[2]; } u;
          u.v = *(const s16x8*)((const char*)vbuf + ((d*128 + c*16) ^ ((d&7)<<4)));
          size_t base = ((size_t)(call*NBC + bc0)*128 + d)*1600 + m*100 + n0;
          if (n0 != 96){
            *(s16x8*)(Vt + base) = u.v;
          } else {
            *(s16x4*)(Vt + base) = u.h[0];
            *(s16x4*)(Vt + ((size_t)(call*NBC + bc0 + 1)*128 + d)*1600 + m*100) = u.h[1];
          }
        }
      }
      if (bn2 != 3){
        asm volatile("s_waitcnt lgkmcnt(0)" ::: "memory");
        __builtin_amdgcn_s_barrier();
      }
    }
  }
}

// ---------------- MFMA flash attention ----------------
__global__ __launch_bounds__(256, 4) void k_attn3(
    const unsigned short* __restrict__ BIG,
    const unsigned short* __restrict__ Kg,
    const unsigned short* __restrict__ Vt,
    unsigned short* __restrict__ BIGo)
{
  int h = blockIdx.x, bc = blockIdx.y, call = blockIdx.z;
  int t = threadIdx.x;
  int wv = t >> 6, l = t & 63;
  int lane31 = l & 31, hi = l >> 5;
  int qoff = call*128, ooff = 512 + call*128;
  __shared__ float xch[4][32];

  const unsigned short* Kh = Kg + (((size_t)(call*NBC + bc))*8 + h)*1600*16;
  const unsigned short* Vh = Vt + ((((size_t)(call*NBC + bc))*8 + h)*16)*1600;

  int qrow = wv*32 + lane31;
  bf16x8 qf = {};
  if (qrow < NN)
    qf = *(const bf16x8*)(BIG + (size_t)(bc*NN + qrow)*768 + qoff + h*NHD + hi*8);

  f32x16 acc = {};
  float m = -1e30f, lsum = 0.f;
  const f32x16 zero16 = {};

  for (int cc0 = 0; cc0 < NN*NM; cc0 += 64){
    bf16x8 kf0 = *(const bf16x8*)(Kh + (size_t)(cc0 + lane31)*16 + hi*8);
    bf16x8 kf1 = *(const bf16x8*)(Kh + (size_t)(cc0 + 32 + lane31)*16 + hi*8);
    bf16x8 vfr[4];
    int vd = lane31 & 15;
#pragma unroll
    for (int ks=0; ks<4; ks++)
      vfr[ks] = *(const bf16x8*)(Vh + (size_t)vd*1600 + cc0 + ks*16 + hi*8);

    f32x16 s0 = __builtin_amdgcn_mfma_f32_32x32x16_bf16(kf0, qf, zero16, 0, 0, 0);
    f32x16 s1 = __builtin_amdgcn_mfma_f32_32x32x16_bf16(kf1, qf, zero16, 0, 0, 0);
    float p[32];
#pragma unroll
    for (int r2=0;r2<16;r2++){ p[r2] = s0[r2]; p[16+r2] = s1[r2]; }

    float pm = p[0];
#pragma unroll
    for (int r2=1;r2<32;r2++) pm = fmaxf(pm, p[r2]);
    pm = fmaxf(pm, __shfl_xor(pm, 32));

    if (__any(pm > m + 8.f)){
      float M = fmaxf(m, pm);
      float alpha = __expf(m - M);
      lsum *= alpha;
      if (l < 32) xch[wv][l] = alpha;
#pragma unroll
      for (int r2=0;r2<16;r2++)
        acc[r2] *= xch[wv][(r2&3) + 8*(r2>>2) + 4*hi];
      m = M;
    }
#pragma unroll
    for (int r2=0;r2<32;r2++){
      p[r2] = __expf(p[r2] - m);
      lsum += p[r2];
    }

#pragma unroll
    for (int ks=0; ks<4; ks++){
      unsigned int a, b, c, dd, sa, sb, sc2, sd;
      asm("v_cvt_pk_bf16_f32 %0, %1, %2" : "=v"(a)  : "v"(p[8*ks+0]), "v"(p[8*ks+1]));
      asm("v_cvt_pk_bf16_f32 %0, %1, %2" : "=v"(b)  : "v"(p[8*ks+4]), "v"(p[8*ks+5]));
      asm("v_cvt_pk_bf16_f32 %0, %1, %2" : "=v"(c)  : "v"(p[8*ks+2]), "v"(p[8*ks+3]));
      asm("v_cvt_pk_bf16_f32 %0, %1, %2" : "=v"(dd) : "v"(p[8*ks+6]), "v"(p[8*ks+7]));
      sa = __shfl_xor(a, 32); sb = __shfl_xor(b, 32);
      sc2 = __shfl_xor(c, 32); sd = __shfl_xor(dd, 32);
      union { unsigned int u[4]; bf16x8 v; } pu;
      pu.u[0] = hi ? sb : a;
      pu.u[1] = hi ? sd : c;
      pu.u[2] = hi ? b  : sa;
      pu.u[3] = hi ? dd : sc2;
      acc = __builtin_amdgcn_mfma_f32_32x32x16_bf16(pu.v, vfr[ks], acc, 0, 0, 0);
    }
  }

  lsum += __shfl_xor(lsum, 32);
  float inv = 1.f / lsum;
  if (l < 32) xch[wv][l] = inv;
  if (lane31 < 16){
    int d = lane31;
#pragma unroll
    for (int r2=0;r2<16;r2++){
      int q = (r2&3) + 8*(r2>>2) + 4*hi;
      int qr2 = wv*32 + q;
      if (qr2 < NN){
        float iv = xch[wv][q];
        BIGo[(size_t)(bc*NN + qr2)*768 + ooff + h*NHD + d] = f2bf(acc[r2]*iv);
      }
    }
  }
}

extern "C" void kernel_launch(void* const* d_in, const int* in_sizes, int n_in,
                              void* d_out, int out_size, void* d_ws, size_t ws_size,
                              hipStream_t stream){
  const float* xp     = (const float*)d_in[0];
  const float* fw     = (const float*)d_in[1];
  const float* temp_r = (const float*)d_in[2];
  const float* temp_i = (const float*)d_in[3];
  const float* fc1_wr=(const float*)d_in[4],  *fc1_wi=(const float*)d_in[5],
             *fc1_br=(const float*)d_in[6],  *fc1_bi=(const float*)d_in[7];
  const float* fc2_wr=(const float*)d_in[8],  *fc2_wi=(const float*)d_in[9],
             *fc2_br=(const float*)d_in[10], *fc2_bi=(const float*)d_in[11];
  const float* fc3_wr=(const float*)d_in[12], *fc3_wi=(const float*)d_in[13],
             *fc3_br=(const float*)d_in[14], *fc3_bi=(const float*)d_in[15];
  const float* fc4_wr=(const float*)d_in[16], *fc4_wi=(const float*)d_in[17],
             *fc4_br=(const float*)d_in[18], *fc4_bi=(const float*)d_in[19];
  const float* fc5_wr=(const float*)d_in[20], *fc5_wi=(const float*)d_in[21],
             *fc5_br=(const float*)d_in[22], *fc5_bi=(const float*)d_in[23];
  const float* ra_wq=(const float*)d_in[24], *ra_bq=(const float*)d_in[25],
             *ra_wk=(const float*)d_in[26], *ra_bk=(const float*)d_in[27],
             *ra_wv=(const float*)d_in[28], *ra_bv=(const float*)d_in[29],
             *ra_wo=(const float*)d_in[30], *ra_bo=(const float*)d_in[31];
  const float* ia_wq=(const float*)d_in[32], *ia_bq=(const float*)d_in[33],
             *ia_wk=(const float*)d_in[34], *ia_bk=(const float*)d_in[35],
             *ia_wv=(const float*)d_in[36], *ia_bv=(const float*)d_in[37],
             *ia_wo=(const float*)d_in[38], *ia_bo=(const float*)d_in[39];
  const float* op1_w=(const float*)d_in[40], *op1_b=(const float*)d_in[41],
             *op2_w=(const float*)d_in[42], *op2_b=(const float*)d_in[43];
  float* out = (float*)d_out;

  char* ws = (char*)d_ws;
  size_t off = 0;
  auto alloc = [&](size_t bytes)->char*{
    char* p = ws + off;
    off += (bytes + 255) & ~(size_t)255;
    return p;
  };
  unsigned short* Tt     = (unsigned short*)alloc((size_t)256*KP1*2);
  unsigned short* Wbig   = (unsigned short*)alloc((size_t)4096*KP1*2);
  unsigned short* Wbig2f = (unsigned short*)alloc((size_t)4096*NL*2);
  unsigned short* comb2f = (unsigned short*)alloc((size_t)512*256*2);
  float* cbias= (float*)alloc((size_t)4*ND*4);
  unsigned short* Wg1    = (unsigned short*)alloc((size_t)256*KP1*2);
  unsigned short* Wg1f   = (unsigned short*)alloc((size_t)256*NL*2);
  unsigned short* Wg2    = (unsigned short*)alloc((size_t)512*256*2);
  float* bg2  = (float*)alloc((size_t)512*4);
  float* A_   = (float*)alloc((size_t)NL*ND*4);
  float* B_   = (float*)alloc((size_t)NL*ND*4);
  float* c0_  = (float*)alloc((size_t)NL*4);
  unsigned short* WT1    = (unsigned short*)alloc((size_t)256*512*2);
  float* bT1  = (float*)alloc((size_t)256*4);
  unsigned short* Wop1   = (unsigned short*)alloc((size_t)384*NL*2);
  unsigned short* Wop2   = (unsigned short*)alloc((size_t)128*384*2);
  unsigned short* Xpb    = (unsigned short*)alloc((size_t)NR*NL*2);
  unsigned short* Xpbf   = (unsigned short*)alloc((size_t)NR*NL*2);
  unsigned short* actg   = (unsigned short*)alloc((size_t)NR*256*2);
  unsigned short* Kg     = (unsigned short*)alloc((size_t)2*NBC*NH*1600*16*2);
  unsigned short* Vt     = (unsigned short*)alloc((size_t)2*NBC*NH*16*1600*2);
  unsigned short* BIG    = (unsigned short*)alloc((size_t)NR*768*2);
  unsigned short* C1     = (unsigned short*)alloc((size_t)NR*256*2);
  unsigned short* hbuf   = (unsigned short*)alloc((size_t)NR*384*2);

  // --- precompute ---
  k_prep<<<5688, 256, 0, stream>>>(fw, fc1_wr, fc1_wi, temp_r, temp_i,
                                   fc4_wr, fc4_wi, op1_w, op2_w, xp,
                                   Tt, Wbig, Wg1, Wop1, Wop2, Xpb, Xpbf);
  k_prep2<<<1736, 256, 0, stream>>>(fc2_wr, fc2_wi, fc2_br, fc2_bi,
                                    ra_wk, ra_bk, ra_wv, ra_bv,
                                    ia_wk, ia_bk, ia_wv, ia_bv,
                                    fc5_wr, fc5_wi, fc5_br, fc5_bi,
                                    ra_wq, ra_bq, ia_wq, ia_bq,
                                    fc3_wr, fc3_wi, fc3_br, fc3_bi,
                                    comb2f, cbias, Wg2, bg2, A_, B_, c0_);
  k_wt1<<<256, 512, 0, stream>>>(A_, B_, c0_, ra_wo, ra_bo, ia_wo, ia_bo, WT1, bT1);
  // DFT fold: Wbig2f = (Wbig @ Tt^T) fragment-major (MODE 7); Wg1f row-major (MODE 6)
  k_gemm<128,KP1,7><<<dim3(32, 2), 256, 0, stream>>>(Wbig, KP1, Tt, nullptr, nullptr, Wbig2f, NL);
  k_gemm<128,KP1,6><<<dim3(2, 2), 256, 0, stream>>>(Wg1, KP1, Tt, nullptr, nullptr, Wg1f, NL);

  // --- data path ---
  k_gemm<64,NL,1><<<dim3(100, 2), 256, 0, stream>>>(Xpb, NL, Wg1f, fc4_br, fc4_bi, actg, 256);
  k_gemm<64,256,2><<<dim3(100, 4), 256, 0, stream>>>(actg, 256, Wg2, bg2, nullptr, BIG, 768);
  k_fuse<<<dim3(100, NM), 256, 0, stream>>>(Xpbf, Wbig2f, fc1_br, fc1_bi, comb2f, cbias, Kg, Vt);
  k_attn3<<<dim3(NH, NBC, 2), 256, 0, stream>>>(BIG, Kg, Vt, BIG);
  k_gemm<64,512,2><<<dim3(100, 2), 256, 0, stream>>>(BIG+256, 768, WT1, bT1, nullptr, C1, 256);
  k_gemm<64,192,3><<<dim3(100, 3), 256, 0, stream>>>(C1, 256, Wop1, op1_b, nullptr, hbuf, 384);
  k_gemm<64,384,4><<<dim3(100, 1), 256, 0, stream>>>(hbuf, 384, Wop2, op2_b, nullptr, out, NP);
}

// Round 2
// 198.173 us; speedup vs baseline: 1.2019x; 1.2019x over previous
//
#include <hip/hip_runtime.h>
#include <hip/hip_bf16.h>

#define NB 16
#define NC 4
#define NN 100
#define NL 192
#define NF 97
#define ND 128
#define NM 16
#define NH 8
#define NHD 16
#define NP 96
#define NR (NB*NC*NN)   /* 6400 */
#define NBC (NB*NC)     /* 64 */
#define KP1 224         /* padded K for weight-space: [xr(97)|xi(97)|pad(30)] */

typedef __bf16 bf16x8 __attribute__((ext_vector_type(8)));
typedef float f32x4 __attribute__((ext_vector_type(4)));
typedef float f32x16 __attribute__((ext_vector_type(16)));
typedef short s16x8 __attribute__((ext_vector_type(8)));
typedef short s16x4 __attribute__((ext_vector_type(4)));
typedef float f32x4v __attribute__((ext_vector_type(4)));

__device__ __forceinline__ float bf2f(unsigned short u){
  union { unsigned int i; float f; } x; x.i = ((unsigned int)u) << 16; return x.f;
}
__device__ __forceinline__ unsigned short f2bf(float v){
  __hip_bfloat16 h = __float2bfloat16(v);
  return *reinterpret_cast<unsigned short*>(&h);
}

// ---------------- merged elementwise precompute: tt | wbig | wg1 | wop | cast ----------------
__global__ void k_prep(const float* __restrict__ fw,
                       const float* __restrict__ fc1_wr, const float* __restrict__ fc1_wi,
                       const float* __restrict__ tr_, const float* __restrict__ ti_,
                       const float* __restrict__ fc4_wr, const float* __restrict__ fc4_wi,
                       const float* __restrict__ op1_w, const float* __restrict__ op2_w,
                       const float* __restrict__ xp,
                       unsigned short* __restrict__ Tt, unsigned short* __restrict__ Wbig,
                       unsigned short* __restrict__ Wg1,
                       unsigned short* __restrict__ Wop1, unsigned short* __restrict__ Wop2,
                       unsigned short* __restrict__ Xpb, unsigned short* __restrict__ Xpbf){
  int b = blockIdx.x, c = threadIdx.x;
  if (b < 256){                                  // Tt[256,224]
    if (c >= KP1) return;
    int l = b;
    float v = 0.f;
    if (l < NL && c < 2*NF){
      int f = (c < NF) ? c : c - NF;
      float s = 1.f/(1.f+expf(-fw[f]));
      int ph = (f*l) % NL;
      float ang = (float)ph * (6.283185307179586f/(float)NL);
      float sv, cv; sincosf(ang, &sv, &cv);
      v = (c < NF) ? s*cv : -s*sv;
    }
    Tt[(size_t)l*KP1 + c] = f2bf(v);
  } else if (b < 256+4096){                      // Wbig[4096,224]
    if (c >= KP1) return;
    int nIdx = b - 256;
    int m = nIdx >> 8, p = (nIdx >> 7) & 1, d = nIdx & 127;
    float v = 0.f;
    if (c < 2*NF){
      int f = (c < NF) ? c : c - NF;
      float tr = tr_[m*NF+f], ti = ti_[m*NF+f];
      float wr_ = fc1_wr[d*NF+f], wi_ = fc1_wi[d*NF+f];
      float w1r = tr*wr_ - ti*wi_;
      float w1i = tr*wi_ + ti*wr_;
      if (p == 0) v = (c < NF) ? w1r : -w1i;
      else        v = (c < NF) ? w1i :  w1r;
    }
    Wbig[(size_t)nIdx*KP1 + c] = f2bf(v);
  } else if (b < 256+4096+256){                  // Wg1[256,224]
    if (c >= KP1) return;
    int n = b - (256+4096);
    int p = n >> 7, d = n & 127;
    float v = 0.f;
    if (c < NF) v = p ? fc4_wi[d*NF+c] : fc4_wr[d*NF+c];
    else if (c < 2*NF){
      int f = c - NF;
      v = p ? fc4_wr[d*NF+f] : -fc4_wi[d*NF+f];
    }
    Wg1[(size_t)n*KP1 + c] = f2bf(v);
  } else if (b < 4608+480){                      // wop casts
    int i = (b-4608)*256 + c;
    const int N1 = 384*NL;
    if (i < N1){ Wop1[i] = f2bf(op1_w[i]); return; }
    int j = i - N1;
    if (j < 128*384){
      int n = j / 384, t2 = j - n*384;
      Wop2[j] = f2bf((n < NP) ? op2_w[n*384 + t2] : 0.f);
    }
  } else {                                       // cast xp -> Xpb + Xpbf (600 blocks)
    size_t i = ((size_t)(b-5088)*256 + c)*8;
    f32x4v a = *(const f32x4v*)(xp + i);
    f32x4v bb = *(const f32x4v*)(xp + i + 4);
    s16x8 o;
#pragma unroll
    for (int e=0;e<4;e++){ o[e] = (short)f2bf(a[e]); o[4+e] = (short)f2bf(bb[e]); }
    *(s16x8*)(Xpb + i) = o;
    int row = (int)(i / NL);
    int colg = (int)(i % NL) >> 3;
    int rb = row >> 4, rl = row & 15;
    int ch = colg >> 2, cg = colg & 3;
    int lane = rl + (cg << 4);
    *(s16x8*)(Xpbf + ((((size_t)rb*6 + ch)*64 + lane)*8)) = o;
  }
}

// merged dot-style precompute: comb(+cbias) | wg2(+bg2) | AB
__global__ void k_prep2(const float* __restrict__ fc2_wr, const float* __restrict__ fc2_wi,
                        const float* __restrict__ fc2_br, const float* __restrict__ fc2_bi,
                        const float* __restrict__ ra_wk, const float* __restrict__ ra_bk,
                        const float* __restrict__ ra_wv, const float* __restrict__ ra_bv,
                        const float* __restrict__ ia_wk, const float* __restrict__ ia_bk,
                        const float* __restrict__ ia_wv, const float* __restrict__ ia_bv,
                        const float* __restrict__ fc5_wr, const float* __restrict__ fc5_wi,
                        const float* __restrict__ fc5_br, const float* __restrict__ fc5_bi,
                        const float* __restrict__ ra_wq, const float* __restrict__ ra_bq,
                        const float* __restrict__ ia_wq, const float* __restrict__ ia_bq,
                        const float* __restrict__ fc3_wr, const float* __restrict__ fc3_wi,
                        const float* __restrict__ fc3_br, const float* __restrict__ fc3_bi,
                        unsigned short* __restrict__ comb2f, float* __restrict__ cbias,
                        unsigned short* __restrict__ Wg2, float* __restrict__ bg2,
                        float* __restrict__ A_, float* __restrict__ B_, float* __restrict__ c0_){
  __shared__ float icL[NF], isL[NF];
  int b = blockIdx.x, t = threadIdx.x;
  if (b < 1032){                                  // comb: k = b/8, c = b%8 (k==128 -> cbias)
    if (t >= 128) return;
    int k = b >> 3, c = b & 7, d = t;
    if (k == ND){
      if (c >= 4) return;
      const float* w = ra_wk; const float* bb = ra_bk; const float* fb = fc2_br;
      switch(c){
        case 0: w=ra_wk; bb=ra_bk; fb=fc2_br; break;
        case 1: w=ra_wv; bb=ra_bv; fb=fc2_br; break;
        case 2: w=ia_wk; bb=ia_bk; fb=fc2_bi; break;
        case 3: w=ia_wv; bb=ia_bv; fb=fc2_bi; break;
      }
      float s = bb[d];
      for (int j=0;j<ND;j++) s += w[d*ND+j]*fb[j];
      cbias[c*ND+d] = s;
      return;
    }
    const float* w = ra_wk; const float* f2 = fc2_wr; float sign = 1.f;
    switch(c){
      case 0: w=ra_wk; f2=fc2_wr; sign= 1.f; break;
      case 1: w=ra_wk; f2=fc2_wi; sign=-1.f; break;
      case 2: w=ra_wv; f2=fc2_wr; sign= 1.f; break;
      case 3: w=ra_wv; f2=fc2_wi; sign=-1.f; break;
      case 4: w=ia_wk; f2=fc2_wi; sign= 1.f; break;
      case 5: w=ia_wk; f2=fc2_wr; sign= 1.f; break;
      case 6: w=ia_wv; f2=fc2_wi; sign= 1.f; break;
      case 7: w=ia_wv; f2=fc2_wr; sign= 1.f; break;
    }
    float s = 0.f;
    for (int j=0;j<ND;j++) s += w[d*ND+j]*f2[j*ND+k];
    int cOut = c >> 1, p = c & 1;
    int jj = d >> 4, rl = d & 15;
    int col = p*ND + k;
    int ch = col >> 5, cg = (col >> 3) & 3, e = col & 7;
    int lane = rl + (cg << 4);
    comb2f[((((size_t)(cOut*8 + ch))*8 + jj)*64 + lane)*8 + e] = f2bf(sign*s);
  } else if (b < 1032+512){                       // wg2
    int q = b - 1032, c = t;
    int k = c & 127; bool ti = (c >= 128);
    const float SCL = 0.08838834764831845f;
    float v = 0.f;
    if (q < 128){
      const float* f5 = ti ? fc5_wi : fc5_wr; float sg = ti ? -1.f : 1.f;
      float s = 0.f;
      for (int j=0;j<ND;j++) s += ra_wq[q*ND+j]*f5[j*ND+k];
      v = sg*s*SCL;
    } else if (q < 256){
      int qq = q-128;
      const float* f5 = ti ? fc5_wr : fc5_wi;
      float s = 0.f;
      for (int j=0;j<ND;j++) s += ia_wq[qq*ND+j]*f5[j*ND+k];
      v = s*SCL;
    } else if (q < 384){
      int d = q-256;
      v = ti ? -fc5_wi[d*ND+k] : fc5_wr[d*ND+k];
    } else {
      int d = q-384;
      v = ti ? fc5_wr[d*ND+k] : fc5_wi[d*ND+k];
    }
    Wg2[(size_t)q*256 + c] = f2bf(v);
    if (c == 0){
      float bb;
      if (q < 128){ bb = ra_bq[q]; for (int j=0;j<ND;j++) bb += ra_wq[q*ND+j]*fc5_br[j]; bb *= SCL; }
      else if (q < 256){ int qq=q-128; bb = ia_bq[qq]; for (int j=0;j<ND;j++) bb += ia_wq[qq*ND+j]*fc5_bi[j]; bb *= SCL; }
      else if (q < 384) bb = fc5_br[q-256];
      else bb = fc5_bi[q-384];
      bg2[q] = bb;
    }
  } else {                                        // AB: l = b-1544 (192 blocks)
    int l = b - 1544, d = t;
    if (d < NF){
      float w = ((d==0)||(d==NF-1)) ? 1.f : 2.f;
      w *= (1.f/(float)NL);
      int ph = (d*l) % NL;
      float ang = (float)ph * (6.283185307179586f/(float)NL);
      float sv, cv; sincosf(ang, &sv, &cv);
      icL[d] = w*cv; isL[d] = w*sv;
    }
    __syncthreads();
    if (d < 128){
      float a = 0.f, bb = 0.f;
      for (int f=0;f<NF;f++){
        float ic = icL[f], is = isL[f];
        float wr = fc3_wr[f*ND+d], wi = fc3_wi[f*ND+d];
        a += ic*wr - is*wi;
        bb -= ic*wi + is*wr;
      }
      A_[l*ND+d] = a; B_[l*ND+d] = bb;
      if (d == 0){
        float cc = 0.f;
        for (int f=0;f<NF;f++) cc += icL[f]*fc3_br[f] - isL[f]*fc3_bi[f];
        c0_[l] = cc;
      }
    }
  }
}

__global__ void k_wt1(const float* __restrict__ A_, const float* __restrict__ B_,
                      const float* __restrict__ c0_,
                      const float* __restrict__ ra_wo, const float* __restrict__ ra_bo,
                      const float* __restrict__ ia_wo, const float* __restrict__ ia_bo,
                      unsigned short* __restrict__ WT1, float* __restrict__ bT1){
  int l = blockIdx.x;          // 0..255
  int c = threadIdx.x;         // 0..511
  float v = 0.f;
  if (l < NL){
    if (c < 128) v = A_[l*ND+c];
    else if (c < 256) v = B_[l*ND+(c-128)];
    else if (c < 384){
      int k = c-256; float s = 0.f;
      for (int j=0;j<ND;j++) s += A_[l*ND+j]*ra_wo[j*ND+k];
      v = s;
    } else {
      int k = c-384; float s = 0.f;
      for (int j=0;j<ND;j++) s += B_[l*ND+j]*ia_wo[j*ND+k];
      v = s;
    }
  }
  WT1[(size_t)l*512 + c] = f2bf(v);
  if (c == 0){
    float bb = 0.f;
    if (l < NL){
      bb = c0_[l];
      for (int j=0;j<ND;j++) bb += A_[l*ND+j]*ra_bo[j] + B_[l*ND+j]*ia_bo[j];
    }
    bT1[l] = bb;
  }
}

// ---------------- MFMA GEMM (templated M-tile) ----------------
// MODE 1: dual bias (bit7 of n), relu, bf16 out
// MODE 2: bias b0[n], bf16 out
// MODE 3: bias b0[n], relu, bf16 out
// MODE 4: bias b0[n] (n<96), fp32 out, store guard n<96
// MODE 6: no bias, bf16 out, store guard n<192 (weight-fold, row-major)
// MODE 7: no bias, bf16 out, guard n<192, FRAGMENT-MAJOR store [m][ch][jj][lane][8]
template<int MT, int KT, int MODE>
__global__ __launch_bounds__(256) void k_gemm(
    const unsigned short* __restrict__ A, int lda,
    const unsigned short* __restrict__ Bw,
    const float* __restrict__ b0, const float* __restrict__ b1,
    void* __restrict__ Cv, int ldc)
{
  constexpr int NI = MT/32;                 // M-frags per wave
  __shared__ unsigned short As[MT][40];
  __shared__ unsigned short Bs[128][40];
  int t = threadIdx.x;
  int bm = blockIdx.x, bn = blockIdx.y;
  int w = t >> 6, l = t & 63;
  int wm = w >> 1, wn = w & 1;
  f32x4 acc[NI][4] = {};
  int r0 = t >> 2, c0 = (t & 3) * 8;
  const unsigned short* Ag = A + (size_t)(bm*MT)*lda;
  const unsigned short* Bg = Bw + (size_t)(bn*128)*KT;
  int lr = l & 15, lk = (l >> 4) * 8;
  for (int k0 = 0; k0 < KT; k0 += 32){
    s16x8 a0 = *(const s16x8*)(Ag + (size_t)r0*lda + k0 + c0);
    s16x8 a1;
    if constexpr (MT == 128) a1 = *(const s16x8*)(Ag + (size_t)(r0+64)*lda + k0 + c0);
    s16x8 bv0 = *(const s16x8*)(Bg + (size_t)r0*KT + k0 + c0);
    s16x8 bv1 = *(const s16x8*)(Bg + (size_t)(r0+64)*KT + k0 + c0);
    __syncthreads();
    *(s16x8*)(&As[r0][c0]) = a0;
    if constexpr (MT == 128) *(s16x8*)(&As[r0+64][c0]) = a1;
    *(s16x8*)(&Bs[r0][c0]) = bv0;
    *(s16x8*)(&Bs[r0+64][c0]) = bv1;
    __syncthreads();
    bf16x8 af[NI], bfr[4];
#pragma unroll
    for (int i=0;i<NI;i++) af[i]  = *(const bf16x8*)(&As[wm*(MT/2) + i*16 + lr][lk]);
#pragma unroll
    for (int j=0;j<4;j++) bfr[j] = *(const bf16x8*)(&Bs[wn*64 + j*16 + lr][lk]);
#pragma unroll
    for (int i=0;i<NI;i++)
#pragma unroll
      for (int j=0;j<4;j++)
        acc[i][j] = __builtin_amdgcn_mfma_f32_16x16x32_bf16(af[i], bfr[j], acc[i][j], 0, 0, 0);
  }
  int lr4 = (l >> 4) * 4, lc = l & 15;
#pragma unroll
  for (int i=0;i<NI;i++){
#pragma unroll
    for (int j=0;j<4;j++){
      int n = bn*128 + wn*64 + j*16 + lc;
      float bias;
      if constexpr (MODE == 1) bias = ((n>>7)&1) ? b1[n&127] : b0[n&127];
      else if constexpr (MODE == 4) bias = (n < NP) ? b0[n] : 0.f;
      else if constexpr (MODE == 6 || MODE == 7) bias = 0.f;
      else bias = b0[n];
#pragma unroll
      for (int q=0;q<4;q++){
        int row = bm*MT + wm*(MT/2) + i*16 + lr4 + q;
        float v = acc[i][j][q] + bias;
        if constexpr (MODE == 1 || MODE == 3) v = fmaxf(v, 0.f);
        if constexpr (MODE == 4){
          if (n < NP) ((float*)Cv)[(size_t)row*ldc + n] = v;
        } else if constexpr (MODE == 6){
          if (n < NL) ((unsigned short*)Cv)[(size_t)row*ldc + n] = f2bf(v);
        } else if constexpr (MODE == 7){
          if (n < NL){
            int m2 = row >> 8, rt = row & 255;
            int jj = rt >> 4, rl2 = rt & 15;
            int ch = n >> 5, cg = (n >> 3) & 3, e = n & 7;
            int lane = rl2 + (cg << 4);
            ((unsigned short*)Cv)[((((size_t)(m2*6 + ch))*16 + jj)*64 + lane)*8 + e] = f2bf(v);
          }
        } else {
          ((unsigned short*)Cv)[(size_t)row*ldc + n] = f2bf(v);
        }
      }
    }
  }
}

// ---------------- fused delay path v9: wave-distinct L2 reads, v7 store patterns ----------------
// grid (100, 16 m); K/V key index kk = m*100 + n
// Each wave owns a distinct column slice in BOTH phases -> no duplicated
// comb2f/Wbig2f L2 reads within a block (v7 read each twice).
__global__ __launch_bounds__(256, 4) void k_fuse(
    const unsigned short* __restrict__ Xpbf,    // [400][6][64][8] fragment-major
    const unsigned short* __restrict__ Wbig2f,  // [16][6][16][64][8] fragment-major
    const float* __restrict__ fc1_br, const float* __restrict__ fc1_bi,
    const unsigned short* __restrict__ comb2f,  // [4][8][8][64][8] fragment-major
    const float* __restrict__ cbias,            // [512]
    unsigned short* __restrict__ Kg,            // [2][64][8][1600][16]
    unsigned short* __restrict__ Vt)            // [2][64][8][16][1600]
{
  __shared__ unsigned short act2f[8][4][64][8]; // fragment-major act, 32768 B
  int t = threadIdx.x;
  int bm = blockIdx.x, m = blockIdx.y;
  int w = t >> 6, l = t & 63;
  int lc = l & 15, lr4 = (l >> 4) * 4;
  int rbase = bm*64;

  // ---------- phase 1: act[64][256] = relu(X @ Wm^T + b) ----------
  // wave w computes all 64 rows x cols [w*64, w*64+64); Wbig2f reads wave-distinct
  f32x4 acc1[4][4] = {};
  const unsigned short* Af = Xpbf + ((size_t)(bm*4)*6)*512;       // frag stride 64*8=512
  const unsigned short* Bf = Wbig2f + ((size_t)m*6)*16*512;
#pragma unroll 2
  for (int ch = 0; ch < 6; ch++){
    bf16x8 af[4], bfj[4];
#pragma unroll
    for (int i=0;i<4;i++)
      af[i] = *(const bf16x8*)(Af + ((size_t)i*6 + ch)*512 + l*8);
#pragma unroll
    for (int j=0;j<4;j++)
      bfj[j] = *(const bf16x8*)(Bf + ((size_t)ch*16 + w*4 + j)*512 + l*8);
#pragma unroll
    for (int i=0;i<4;i++)
#pragma unroll
      for (int j=0;j<4;j++)
        acc1[i][j] = __builtin_amdgcn_mfma_f32_16x16x32_bf16(af[i], bfj[j], acc1[i][j], 0, 0, 0);
  }
  // epilogue 1: bias + relu -> act2f (fragment-major)
#pragma unroll
  for (int i=0;i<4;i++){
#pragma unroll
    for (int j=0;j<4;j++){
      int col = w*64 + j*16 + lc;
      float bias = ((col>>7)&1) ? fc1_bi[col&127] : fc1_br[col&127];
      int ch = col >> 5, cg = (col >> 3) & 3, e = col & 7;
#pragma unroll
      for (int q=0;q<4;q++)
        act2f[ch][i][(lr4 + q) + (cg << 4)][e] = f2bf(fmaxf(acc1[i][j][q] + bias, 0.f));
    }
  }
  __syncthreads();

  // ---------- phase 2: KV[64][512] in 4 n-tiles; K tiles operand-swapped ----------
  // wave w owns n2 cols [w*32, w*32+32) -> comb2f reads wave-distinct
  for (int bn2 = 0; bn2 < 4; bn2++){
    const unsigned short* Cf = comb2f + ((size_t)bn2*8)*8*512;
    int call = bn2 >> 1, isV = bn2 & 1;
    if (!isV){
      // K: C^T = comb x act -> quad spans d; dense 8B vector stores (512B/instr/wave)
      f32x4 accS[2][4] = {};
#pragma unroll 4
      for (int ch = 0; ch < 8; ch++){
        bf16x8 af[4], bfr[2];
#pragma unroll
        for (int i=0;i<4;i++)
          af[i] = *(const bf16x8*)(&act2f[ch][i][l][0]);
#pragma unroll
        for (int j=0;j<2;j++)
          bfr[j] = *(const bf16x8*)(Cf + ((size_t)ch*8 + w*2 + j)*512 + l*8);
#pragma unroll
        for (int j=0;j<2;j++)
#pragma unroll
          for (int i=0;i<4;i++)
            accS[j][i] = __builtin_amdgcn_mfma_f32_16x16x32_bf16(bfr[j], af[i], accS[j][i], 0, 0, 0);
      }
#pragma unroll
      for (int j=0;j<2;j++){
        int n2q = w*32 + j*16 + lr4;           // quad base in n2 (d dim)
        f32x4v cb4 = *(const f32x4v*)(cbias + bn2*128 + n2q);
        int h = n2q >> 4, d0 = n2q & 15;
#pragma unroll
        for (int i=0;i<4;i++){
          int rr = rbase + i*16 + lc;
          int bc = rr/100, n = rr - bc*100;
          int kk = m*100 + n;
          s16x4 v4;
#pragma unroll
          for (int q=0;q<4;q++) v4[q] = (short)f2bf(accS[j][i][q] + cb4[q]);
          *(s16x4*)(Kg + ((((size_t)(call*NBC + bc))*8 + h)*1600 + kk)*16 + d0) = v4;
        }
      }
    } else {
      // V: normal orientation -> quad spans kk; 8B vector stores into [d][kk]
      f32x4 acc[4][2] = {};
#pragma unroll 4
      for (int ch = 0; ch < 8; ch++){
        bf16x8 af[4], bfr[2];
#pragma unroll
        for (int i=0;i<4;i++)
          af[i] = *(const bf16x8*)(&act2f[ch][i][l][0]);
#pragma unroll
        for (int j=0;j<2;j++)
          bfr[j] = *(const bf16x8*)(Cf + ((size_t)ch*8 + w*2 + j)*512 + l*8);
#pragma unroll
        for (int i=0;i<4;i++)
#pragma unroll
          for (int j=0;j<2;j++)
            acc[i][j] = __builtin_amdgcn_mfma_f32_16x16x32_bf16(af[i], bfr[j], acc[i][j], 0, 0, 0);
      }
#pragma unroll
      for (int i=0;i<4;i++){
        int rr0 = rbase + i*16 + lr4;          // quad never straddles bc (100 % 4 == 0)
        int bc = rr0/100, n = rr0 - bc*100;
        int kk = m*100 + n;
#pragma unroll
        for (int j=0;j<2;j++){
          int n2 = w*32 + j*16 + lc;
          float bias = cbias[bn2*128 + n2];
          s16x4 v4;
#pragma unroll
          for (int q=0;q<4;q++) v4[q] = (short)f2bf(acc[i][j][q] + bias);
          *(s16x4*)(Vt + ((size_t)(call*NBC + bc)*128 + n2)*1600 + kk) = v4;
        }
      }
    }
  }
}

// ---------------- MFMA flash attention ----------------
__global__ __launch_bounds__(256, 4) void k_attn3(
    const unsigned short* __restrict__ BIG,
    const unsigned short* __restrict__ Kg,
    const unsigned short* __restrict__ Vt,
    unsigned short* __restrict__ BIGo)
{
  int h = blockIdx.x, bc = blockIdx.y, call = blockIdx.z;
  int t = threadIdx.x;
  int wv = t >> 6, l = t & 63;
  int lane31 = l & 31, hi = l >> 5;
  int qoff = call*128, ooff = 512 + call*128;
  __shared__ float xch[4][32];

  const unsigned short* Kh = Kg + (((size_t)(call*NBC + bc))*8 + h)*1600*16;
  const unsigned short* Vh = Vt + ((((size_t)(call*NBC + bc))*8 + h)*16)*1600;

  int qrow = wv*32 + lane31;
  bf16x8 qf = {};
  if (qrow < NN)
    qf = *(const bf16x8*)(BIG + (size_t)(bc*NN + qrow)*768 + qoff + h*NHD + hi*8);

  f32x16 acc = {};
  float m = -1e30f, lsum = 0.f;
  const f32x16 zero16 = {};

  for (int cc0 = 0; cc0 < NN*NM; cc0 += 64){
    bf16x8 kf0 = *(const bf16x8*)(Kh + (size_t)(cc0 + lane31)*16 + hi*8);
    bf16x8 kf1 = *(const bf16x8*)(Kh + (size_t)(cc0 + 32 + lane31)*16 + hi*8);
    bf16x8 vfr[4];
    int vd = lane31 & 15;
#pragma unroll
    for (int ks=0; ks<4; ks++)
      vfr[ks] = *(const bf16x8*)(Vh + (size_t)vd*1600 + cc0 + ks*16 + hi*8);

    f32x16 s0 = __builtin_amdgcn_mfma_f32_32x32x16_bf16(kf0, qf, zero16, 0, 0, 0);
    f32x16 s1 = __builtin_amdgcn_mfma_f32_32x32x16_bf16(kf1, qf, zero16, 0, 0, 0);
    float p[32];
#pragma unroll
    for (int r2=0;r2<16;r2++){ p[r2] = s0[r2]; p[16+r2] = s1[r2]; }

    float pm = p[0];
#pragma unroll
    for (int r2=1;r2<32;r2++) pm = fmaxf(pm, p[r2]);
    pm = fmaxf(pm, __shfl_xor(pm, 32));

    if (__any(pm > m + 8.f)){
      float M = fmaxf(m, pm);
      float alpha = __expf(m - M);
      lsum *= alpha;
      if (l < 32) xch[wv][l] = alpha;
#pragma unroll
      for (int r2=0;r2<16;r2++)
        acc[r2] *= xch[wv][(r2&3) + 8*(r2>>2) + 4*hi];
      m = M;
    }
#pragma unroll
    for (int r2=0;r2<32;r2++){
      p[r2] = __expf(p[r2] - m);
      lsum += p[r2];
    }

#pragma unroll
    for (int ks=0; ks<4; ks++){
      unsigned int a, b, c, dd, sa, sb, sc2, sd;
      asm("v_cvt_pk_bf16_f32 %0, %1, %2" : "=v"(a)  : "v"(p[8*ks+0]), "v"(p[8*ks+1]));
      asm("v_cvt_pk_bf16_f32 %0, %1, %2" : "=v"(b)  : "v"(p[8*ks+4]), "v"(p[8*ks+5]));
      asm("v_cvt_pk_bf16_f32 %0, %1, %2" : "=v"(c)  : "v"(p[8*ks+2]), "v"(p[8*ks+3]));
      asm("v_cvt_pk_bf16_f32 %0, %1, %2" : "=v"(dd) : "v"(p[8*ks+6]), "v"(p[8*ks+7]));
      sa = __shfl_xor(a, 32); sb = __shfl_xor(b, 32);
      sc2 = __shfl_xor(c, 32); sd = __shfl_xor(dd, 32);
      union { unsigned int u[4]; bf16x8 v; } pu;
      pu.u[0] = hi ? sb : a;
      pu.u[1] = hi ? sd : c;
      pu.u[2] = hi ? b  : sa;
      pu.u[3] = hi ? dd : sc2;
      acc = __builtin_amdgcn_mfma_f32_32x32x16_bf16(pu.v, vfr[ks], acc, 0, 0, 0);
    }
  }

  lsum += __shfl_xor(lsum, 32);
  float inv = 1.f / lsum;
  if (l < 32) xch[wv][l] = inv;
  if (lane31 < 16){
    int d = lane31;
#pragma unroll
    for (int r2=0;r2<16;r2++){
      int q = (r2&3) + 8*(r2>>2) + 4*hi;
      int qr2 = wv*32 + q;
      if (qr2 < NN){
        float iv = xch[wv][q];
        BIGo[(size_t)(bc*NN + qr2)*768 + ooff + h*NHD + d] = f2bf(acc[r2]*iv);
      }
    }
  }
}

extern "C" void kernel_launch(void* const* d_in, const int* in_sizes, int n_in,
                              void* d_out, int out_size, void* d_ws, size_t ws_size,
                              hipStream_t stream){
  const float* xp     = (const float*)d_in[0];
  const float* fw     = (const float*)d_in[1];
  const float* temp_r = (const float*)d_in[2];
  const float* temp_i = (const float*)d_in[3];
  const float* fc1_wr=(const float*)d_in[4],  *fc1_wi=(const float*)d_in[5],
             *fc1_br=(const float*)d_in[6],  *fc1_bi=(const float*)d_in[7];
  const float* fc2_wr=(const float*)d_in[8],  *fc2_wi=(const float*)d_in[9],
             *fc2_br=(const float*)d_in[10], *fc2_bi=(const float*)d_in[11];
  const float* fc3_wr=(const float*)d_in[12], *fc3_wi=(const float*)d_in[13],
             *fc3_br=(const float*)d_in[14], *fc3_bi=(const float*)d_in[15];
  const float* fc4_wr=(const float*)d_in[16], *fc4_wi=(const float*)d_in[17],
             *fc4_br=(const float*)d_in[18], *fc4_bi=(const float*)d_in[19];
  const float* fc5_wr=(const float*)d_in[20], *fc5_wi=(const float*)d_in[21],
             *fc5_br=(const float*)d_in[22], *fc5_bi=(const float*)d_in[23];
  const float* ra_wq=(const float*)d_in[24], *ra_bq=(const float*)d_in[25],
             *ra_wk=(const float*)d_in[26], *ra_bk=(const float*)d_in[27],
             *ra_wv=(const float*)d_in[28], *ra_bv=(const float*)d_in[29],
             *ra_wo=(const float*)d_in[30], *ra_bo=(const float*)d_in[31];
  const float* ia_wq=(const float*)d_in[32], *ia_bq=(const float*)d_in[33],
             *ia_wk=(const float*)d_in[34], *ia_bk=(const float*)d_in[35],
             *ia_wv=(const float*)d_in[36], *ia_bv=(const float*)d_in[37],
             *ia_wo=(const float*)d_in[38], *ia_bo=(const float*)d_in[39];
  const float* op1_w=(const float*)d_in[40], *op1_b=(const float*)d_in[41],
             *op2_w=(const float*)d_in[42], *op2_b=(const float*)d_in[43];
  float* out = (float*)d_out;

  char* ws = (char*)d_ws;
  size_t off = 0;
  auto alloc = [&](size_t bytes)->char*{
    char* p = ws + off;
    off += (bytes + 255) & ~(size_t)255;
    return p;
  };
  unsigned short* Tt     = (unsigned short*)alloc((size_t)256*KP1*2);
  unsigned short* Wbig   = (unsigned short*)alloc((size_t)4096*KP1*2);
  unsigned short* Wbig2f = (unsigned short*)alloc((size_t)4096*NL*2);
  unsigned short* comb2f = (unsigned short*)alloc((size_t)512*256*2);
  float* cbias= (float*)alloc((size_t)4*ND*4);
  unsigned short* Wg1    = (unsigned short*)alloc((size_t)256*KP1*2);
  unsigned short* Wg1f   = (unsigned short*)alloc((size_t)256*NL*2);
  unsigned short* Wg2    = (unsigned short*)alloc((size_t)512*256*2);
  float* bg2  = (float*)alloc((size_t)512*4);
  float* A_   = (float*)alloc((size_t)NL*ND*4);
  float* B_   = (float*)alloc((size_t)NL*ND*4);
  float* c0_  = (float*)alloc((size_t)NL*4);
  unsigned short* WT1    = (unsigned short*)alloc((size_t)256*512*2);
  float* bT1  = (float*)alloc((size_t)256*4);
  unsigned short* Wop1   = (unsigned short*)alloc((size_t)384*NL*2);
  unsigned short* Wop2   = (unsigned short*)alloc((size_t)128*384*2);
  unsigned short* Xpb    = (unsigned short*)alloc((size_t)NR*NL*2);
  unsigned short* Xpbf   = (unsigned short*)alloc((size_t)NR*NL*2);
  unsigned short* actg   = (unsigned short*)alloc((size_t)NR*256*2);
  unsigned short* Kg     = (unsigned short*)alloc((size_t)2*NBC*NH*1600*16*2);
  unsigned short* Vt     = (unsigned short*)alloc((size_t)2*NBC*NH*16*1600*2);
  unsigned short* BIG    = (unsigned short*)alloc((size_t)NR*768*2);
  unsigned short* C1     = (unsigned short*)alloc((size_t)NR*256*2);
  unsigned short* hbuf   = (unsigned short*)alloc((size_t)NR*384*2);

  // --- precompute ---
  k_prep<<<5688, 256, 0, stream>>>(fw, fc1_wr, fc1_wi, temp_r, temp_i,
                                   fc4_wr, fc4_wi, op1_w, op2_w, xp,
                                   Tt, Wbig, Wg1, Wop1, Wop2, Xpb, Xpbf);
  k_prep2<<<1736, 256, 0, stream>>>(fc2_wr, fc2_wi, fc2_br, fc2_bi,
                                    ra_wk, ra_bk, ra_wv, ra_bv,
                                    ia_wk, ia_bk, ia_wv, ia_bv,
                                    fc5_wr, fc5_wi, fc5_br, fc5_bi,
                                    ra_wq, ra_bq, ia_wq, ia_bq,
                                    fc3_wr, fc3_wi, fc3_br, fc3_bi,
                                    comb2f, cbias, Wg2, bg2, A_, B_, c0_);
  k_wt1<<<256, 512, 0, stream>>>(A_, B_, c0_, ra_wo, ra_bo, ia_wo, ia_bo, WT1, bT1);
  // DFT fold: Wbig2f = (Wbig @ Tt^T) fragment-major (MODE 7); Wg1f row-major (MODE 6)
  k_gemm<128,KP1,7><<<dim3(32, 2), 256, 0, stream>>>(Wbig, KP1, Tt, nullptr, nullptr, Wbig2f, NL);
  k_gemm<128,KP1,6><<<dim3(2, 2), 256, 0, stream>>>(Wg1, KP1, Tt, nullptr, nullptr, Wg1f, NL);

  // --- data path ---
  k_gemm<64,NL,1><<<dim3(100, 2), 256, 0, stream>>>(Xpb, NL, Wg1f, fc4_br, fc4_bi, actg, 256);
  k_gemm<64,256,2><<<dim3(100, 4), 256, 0, stream>>>(actg, 256, Wg2, bg2, nullptr, BIG, 768);
  k_fuse<<<dim3(100, NM), 256, 0, stream>>>(Xpbf, Wbig2f, fc1_br, fc1_bi, comb2f, cbias, Kg, Vt);
  k_attn3<<<dim3(NH, NBC, 2), 256, 0, stream>>>(BIG, Kg, Vt, BIG);
  k_gemm<64,512,2><<<dim3(100, 2), 256, 0, stream>>>(BIG+256, 768, WT1, bT1, nullptr, C1, 256);
  k_gemm<64,192,3><<<dim3(100, 3), 256, 0, stream>>>(C1, 256, Wop1, op1_b, nullptr, hbuf, 384);
  k_gemm<64,384,4><<<dim3(100, 1), 256, 0, stream>>>(hbuf, 384, Wop2, op2_b, nullptr, out, NP);
}